// Round 4
// baseline (685.378 us; speedup 1.0000x reference)
//
#include <hip/hip_runtime.h>

// GraphSAGE 2-layer encoder, MI355X (gfx950).  Round 6.
// vs R5: gemm1's A-staging restored to async global_load_lds, but keeping the
// direct-fp32-x read (no xbf buffer): A staged as fp32 into LDS with an XOR
// bank-swizzle (unit c' = c ^ (r&7), applied on BOTH the pre-swizzled global
// source and the ds_read side), converted to bf16 in-register at fragment
// read.  Removes the per-K-step sync load->cvt->ds_write latency chain that
// made R5's k_g1f latency-bound (MfmaUtil 11%, VALUBusy 27%, occ 29%).
//   GEMM1: Cl = x@w1_l^T ; Cr = x@w1_r^T + b1          (bf16, [Mpad,256] each)
//   agg1 : h[n] = relu(mean(Cl[src]) + Cr[n])          (bf16 [Mpad,256])
//   agg2 : mean2[n] = mean(h[src])                     (bf16 [Mpad,256])
//   GEMM2: out = [mean2|h] @ [w2_l|w2_r]^T + b2        (fp32 [nN,512])

#define IN_DIM  1024
#define HID_DIM 256
#define OUT_N   512

typedef __attribute__((ext_vector_type(8))) short bf16x8;
typedef __attribute__((ext_vector_type(4))) float f32x4;

static __device__ __forceinline__ unsigned short f2bf(float f) {
  unsigned int u = __float_as_uint(f);
  u += 0x7fffu + ((u >> 16) & 1u);
  return (unsigned short)(u >> 16);
}
static __device__ __forceinline__ float bf2f(unsigned short b) {
  return __uint_as_float(((unsigned int)b) << 16);
}

static __device__ __forceinline__ int load_idx(const void* ei, long long pos, int is64) {
  if (is64) return (int)((const long long*)ei)[pos];
  return ((const int*)ei)[pos];
}

// ---------- fused: dtype detect + weight cvt + degree count ----------
// block 0: detect->flag; [1,513): w1cat; [513,769): w2cat;
// [769, 769+nEb): degree atomics (own per-block detect).
__global__ void k_pre(const unsigned int* __restrict__ eiu, const void* __restrict__ ei,
                      int* __restrict__ flag,
                      const float* __restrict__ w1l, const float* __restrict__ w1r,
                      unsigned short* __restrict__ W1c,
                      const float* __restrict__ w2l, const float* __restrict__ w2r,
                      unsigned short* __restrict__ W2c,
                      int nE, int* __restrict__ deg) {
  int b = blockIdx.x;
  if (b == 0) {
    if (threadIdx.x < 64) {
      unsigned int v = eiu[2 * threadIdx.x + 1];
      unsigned long long m = __ballot(v == 0u);
      if (threadIdx.x == 0) *flag = (m == ~0ull) ? 1 : 0;
    }
    return;
  }
  if (b < 513) {                      // W1cat[n][k], n<256 -> w1_l else w1_r; K=1024
    int i = (b - 1) * 256 + threadIdx.x;
    int base = i * 4;
    int n = base / IN_DIM, k = base % IN_DIM;
    const float* s = (n < HID_DIM) ? &w1l[(size_t)n * IN_DIM + k]
                                   : &w1r[(size_t)(n - HID_DIM) * IN_DIM + k];
    float4 v = *(const float4*)s;
    ushort4 o = { f2bf(v.x), f2bf(v.y), f2bf(v.z), f2bf(v.w) };
    *(ushort4*)&W1c[base] = o;
    return;
  }
  if (b < 769) {                      // W2cat[n][k], k<256 -> w2_l else w2_r; K=512
    int i = (b - 513) * 256 + threadIdx.x;
    int base = i * 4;
    int n = base >> 9, k = base & 511;
    const float* s = (k < HID_DIM) ? &w2l[(size_t)n * HID_DIM + k]
                                   : &w2r[(size_t)n * HID_DIM + (k - HID_DIM)];
    float4 v = *(const float4*)s;
    ushort4 o = { f2bf(v.x), f2bf(v.y), f2bf(v.z), f2bf(v.w) };
    *(ushort4*)&W2c[base] = o;
    return;
  }
  // degree count (per-block dtype detect: no dependency on block 0)
  __shared__ int s_is64;
  if (threadIdx.x < 64) {
    unsigned int v = eiu[2 * threadIdx.x + 1];
    unsigned long long m = __ballot(v == 0u);
    if (threadIdx.x == 0) s_is64 = (m == ~0ull) ? 1 : 0;
  }
  __syncthreads();
  int e = (b - 769) * 256 + threadIdx.x;
  if (e < nE) {
    int d = load_idx(ei, (long long)nE + e, s_is64);
    atomicAdd(&deg[d], 1);
  }
}

// ---------- single-block exclusive scan: deg[padN] -> off[], cursor[] ----------
__global__ __launch_bounds__(1024) void k_scan1(const int* __restrict__ deg,
                                                int* __restrict__ off,
                                                int* __restrict__ cursor, int n4q) {
  const int t = threadIdx.x;
  const int CH = (n4q + 1023) >> 10;    // int4s per thread (13 at padN=50176)
  const int i0 = t * CH;
  int tsum = 0;
  for (int i = 0; i < CH; ++i) {
    int idx = i0 + i;
    if (idx < n4q) {
      int4 d = ((const int4*)deg)[idx];
      tsum += d.x + d.y + d.z + d.w;
    }
  }
  __shared__ int s[1024];
  s[t] = tsum;
  __syncthreads();
  for (int d = 1; d < 1024; d <<= 1) {
    int u = (t >= d) ? s[t - d] : 0;
    __syncthreads();
    s[t] += u;
    __syncthreads();
  }
  int run = (t == 0) ? 0 : s[t - 1];
  for (int i = 0; i < CH; ++i) {
    int idx = i0 + i;
    if (idx < n4q) {
      int4 d = ((const int4*)deg)[idx];
      int4 o;
      o.x = run;
      o.y = run + d.x;
      o.z = o.y + d.y;
      o.w = o.z + d.z;
      run = o.w + d.w;
      ((int4*)off)[idx] = o;
      ((int4*)cursor)[idx] = o;
    }
  }
}

// ---------- GEMM helpers ----------
static __device__ __forceinline__ void load_lds16(const void* g, void* lds) {
  __builtin_amdgcn_global_load_lds(
      (const __attribute__((address_space(1))) unsigned int*)g,
      (__attribute__((address_space(3))) unsigned int*)lds, 16, 0, 0);
}

// bijective XCD-chunk swizzle (m204): consecutive logical tiles land on one XCD
static __device__ __forceinline__ int xcd_swz(int orig, int nwg) {
  const int q = nwg >> 3, r = nwg & 7;
  const int xcd = orig & 7, rk = orig >> 3;
  return (xcd < r) ? xcd * (q + 1) + rk : r * (q + 1) + (xcd - r) * q + rk;
}

// ---------- fused GEMM1 + csr fill ----------
// blocks [0, ngemm): gemm1 tiles (1D, wg>>2 = m-tile, wg&3 = n-tile);
// blocks [ngemm, ...): csr fill (independent of gemm1; consumer agg1 is the
// next dispatch on the stream).
// A is fp32 x, staged async via global_load_lds into a 16KB fp32 LDS tile
// with XOR bank-swizzle: 16B-unit (r, c) stored at physical unit c^(r&7).
// Staging keeps LDS linear and pre-swizzles the per-lane GLOBAL column
// (m173 pattern); the ds_read side applies the same involution.  Conversion
// to bf16 happens at fragment read (bit-identical f2bf to the old xbf path).
__global__ __launch_bounds__(256) void k_g1f(const float* __restrict__ A,
                                             const unsigned short* __restrict__ B,
                                             unsigned short* __restrict__ Cl,
                                             unsigned short* __restrict__ Cr,
                                             const float* __restrict__ b1,
                                             int nNm1, int ngemm,
                                             const void* __restrict__ ei, int nE,
                                             const int* __restrict__ flag,
                                             int* __restrict__ cursor,
                                             int* __restrict__ csr) {
  if ((int)blockIdx.x >= ngemm) {     // ---- csr fill path ----
    int e = ((int)blockIdx.x - ngemm) * 256 + threadIdx.x;
    if (e < nE) {
      int is64 = *flag;
      int s = load_idx(ei, e, is64);
      int d = load_idx(ei, (long long)nE + e, is64);
      int p = atomicAdd(&cursor[d], 1);
      csr[p] = s;
    }
    return;
  }
  __shared__ float Asf[128 * 32];           // 16 KB, swizzled fp32 A tile
  __shared__ unsigned short Bs[128 * 32];   // 8 KB bf16 B tile
  const int tid = threadIdx.x;
  const int w = tid >> 6, l = tid & 63;
  const int wm = w >> 1, wn = w & 1;
  const int quad = l >> 4, lane16 = l & 15;
  const int wg = xcd_swz(blockIdx.x, ngemm);
  const int m0 = (wg >> 2) * 128;
  const int n0 = (wg & 3) * 128;

  // staging geometry: issue (w,it) covers physical units (w*4+it)*64 + l,
  // i.e. rows (w*4+it)*8 + (l>>3), physical unit-in-row l&7.
  const int rl   = l >> 3;                  // r & 7 for this lane
  const int clog = (l & 7) ^ rl;            // logical (pre-swizzled) 4-float unit
  const float* agp[4];
#pragma unroll
  for (int it = 0; it < 4; ++it) {
    const int r = ((w * 4 + it) << 3) + rl;
    int ar = m0 + r;
    if (ar > nNm1) ar = nNm1;               // pad rows: dup data, never read
    agp[it] = A + (size_t)ar * IN_DIM + clog * 4;
  }

  // fragment-read swizzle constants
  const int sA  = lane16 & 7;               // row&7 for all af rows of this lane
  const int au0 = ((quad * 2) ^ sA) << 4;   // byte offset of phys unit for c=quad*2
  const int au1 = au0 ^ 16;                 //            ... for c=quad*2+1

  f32x4 acc[4][4] = {};
  for (int k0 = 0; k0 < IN_DIM; k0 += 32) {
#pragma unroll
    for (int it = 0; it < 4; ++it)          // A: fp32 async, pre-swizzled source
      load_lds16(agp[it] + k0, (char*)Asf + ((w * 4 + it) << 10));
#pragma unroll
    for (int c = 0; c < 2; ++c) {           // B: bf16 async (linear, as before)
      const int flat = ((w * 2 + c) << 10);
      const int fb = flat + l * 16;
      const int row = fb >> 6;
      const int cb = fb & 63;
      load_lds16(B + (size_t)(n0 + row) * IN_DIM + (k0 + (cb >> 1)), (char*)Bs + flat);
    }
    __syncthreads();
    bf16x8 af[4], bfr[4];
#pragma unroll
    for (int i = 0; i < 4; ++i) {
      const int rb = (wm * 64 + i * 16 + lane16) << 7;   // row byte base (128B rows)
      f32x4 lo = *(const f32x4*)((const char*)Asf + rb + au0);  // k = quad*8..+3
      f32x4 hi = *(const f32x4*)((const char*)Asf + rb + au1);  // k = quad*8+4..+7
      bf16x8 t;
      t[0] = (short)f2bf(lo[0]); t[1] = (short)f2bf(lo[1]);
      t[2] = (short)f2bf(lo[2]); t[3] = (short)f2bf(lo[3]);
      t[4] = (short)f2bf(hi[0]); t[5] = (short)f2bf(hi[1]);
      t[6] = (short)f2bf(hi[2]); t[7] = (short)f2bf(hi[3]);
      af[i] = t;
    }
#pragma unroll
    for (int j = 0; j < 4; ++j)
      bfr[j] = *(const bf16x8*)&Bs[(wn * 64 + j * 16 + lane16) * 32 + quad * 8];
#pragma unroll
    for (int i = 0; i < 4; ++i)
#pragma unroll
      for (int j = 0; j < 4; ++j)
        acc[i][j] = __builtin_amdgcn_mfma_f32_16x16x32_bf16(af[i], bfr[j], acc[i][j], 0, 0, 0);
    __syncthreads();
  }

  const bool right = (n0 >= 256);
  unsigned short* Cb = right ? Cr : Cl;
  const int nc0 = n0 - (right ? 256 : 0);
#pragma unroll
  for (int i = 0; i < 4; ++i) {
    const int rbase = m0 + wm * 64 + i * 16 + quad * 4;
#pragma unroll
    for (int j = 0; j < 4; ++j) {
      const int col = nc0 + wn * 64 + j * 16 + lane16;
      const float bv = right ? b1[col] : 0.0f;
#pragma unroll
      for (int r = 0; r < 4; ++r)
        Cb[(size_t)(rbase + r) * HID_DIM + col] = f2bf(acc[i][j][r] + bv);
    }
  }
}

// GEMM2: A k<256 from Am (mean2), k>=256 from Ah (h); B=W2c[512,512]; fp32 out + b2
__global__ __launch_bounds__(256) void k_gemm2(const unsigned short* __restrict__ Am,
                                               const unsigned short* __restrict__ Ah,
                                               const unsigned short* __restrict__ B,
                                               float* __restrict__ out,
                                               const float* __restrict__ b2, int Mstore) {
  __shared__ unsigned short As[128 * 32];
  __shared__ unsigned short Bs[128 * 32];
  const int tid = threadIdx.x;
  const int w = tid >> 6, l = tid & 63;
  const int wm = w >> 1, wn = w & 1;
  const int quad = l >> 4, lane16 = l & 15;
  const int nwg = gridDim.x * gridDim.y;
  const int wg = xcd_swz(blockIdx.y * gridDim.x + blockIdx.x, nwg);
  const int m0 = (wg / gridDim.x) * 128;
  const int n0 = (wg % gridDim.x) * 128;

  f32x4 acc[4][4] = {};
  for (int k0 = 0; k0 < 2 * HID_DIM; k0 += 32) {
    const unsigned short* Abase = (k0 < HID_DIM) ? Am + k0 : Ah + (k0 - HID_DIM);
#pragma unroll
    for (int c = 0; c < 2; ++c) {
      const int flat = ((w * 2 + c) << 10);
      const int fb = flat + l * 16;
      const int row = fb >> 6;
      const int cb = fb & 63;
      load_lds16(Abase + (size_t)(m0 + row) * HID_DIM + (cb >> 1), (char*)As + flat);
      load_lds16(B + (size_t)(n0 + row) * (2 * HID_DIM) + (k0 + (cb >> 1)), (char*)Bs + flat);
    }
    __syncthreads();
    bf16x8 af[4], bfr[4];
#pragma unroll
    for (int i = 0; i < 4; ++i)
      af[i] = *(const bf16x8*)&As[(wm * 64 + i * 16 + lane16) * 32 + quad * 8];
#pragma unroll
    for (int j = 0; j < 4; ++j)
      bfr[j] = *(const bf16x8*)&Bs[(wn * 64 + j * 16 + lane16) * 32 + quad * 8];
#pragma unroll
    for (int i = 0; i < 4; ++i)
#pragma unroll
      for (int j = 0; j < 4; ++j)
        acc[i][j] = __builtin_amdgcn_mfma_f32_16x16x32_bf16(af[i], bfr[j], acc[i][j], 0, 0, 0);
    __syncthreads();
  }

#pragma unroll
  for (int i = 0; i < 4; ++i) {
    const int rbase = m0 + wm * 64 + i * 16 + quad * 4;
#pragma unroll
    for (int j = 0; j < 4; ++j) {
      const int col = n0 + wn * 64 + j * 16 + lane16;
      const float bv = b2[col];
#pragma unroll
      for (int r = 0; r < 4; ++r) {
        const int rowi = rbase + r;
        if (rowi < Mstore) out[(size_t)rowi * OUT_N + col] = acc[i][j][r] + bv;
      }
    }
  }
}

// ---------- aggregations: 1 wave/node, 16B/lane, 8/4/2/1-pair batch cascade ----------
template <int NB>
static __device__ __forceinline__ void gatherN(const unsigned short* __restrict__ src,
                                               const int* __restrict__ csr, int ib,
                                               size_t colb, float* a) {
  bf16x8 v[NB];
#pragma unroll
  for (int u = 0; u < NB; ++u) {
    int r = csr[ib + 2 * u];
    v[u] = *(const bf16x8*)&src[(size_t)r * HID_DIM + colb];
  }
#pragma unroll
  for (int u = 0; u < NB; ++u)
#pragma unroll
    for (int c = 0; c < 8; ++c) a[c] += bf2f((unsigned short)v[u][c]);
}

static __device__ __forceinline__ void agg_sum(const unsigned short* __restrict__ src,
                                               const int* __restrict__ csr,
                                               int s, int e, int half, size_t colb,
                                               float* a) {
  const int cnt = e - s;
  const int P = cnt >> 1;
  const int ib0 = s + half;
  int k = 0;
  for (; k + 8 <= P; k += 8) gatherN<8>(src, csr, ib0 + 2 * k, colb, a);
  if (k + 4 <= P) { gatherN<4>(src, csr, ib0 + 2 * k, colb, a); k += 4; }
  if (k + 2 <= P) { gatherN<2>(src, csr, ib0 + 2 * k, colb, a); k += 2; }
  if (k < P)      { gatherN<1>(src, csr, ib0 + 2 * k, colb, a); }
  if ((cnt & 1) && half == 0) {
    bf16x8 v = *(const bf16x8*)&src[(size_t)csr[e - 1] * HID_DIM + colb];
#pragma unroll
    for (int c = 0; c < 8; ++c) a[c] += bf2f((unsigned short)v[c]);
  }
#pragma unroll
  for (int c = 0; c < 8; ++c) a[c] += __shfl_xor(a[c], 32);
}

__global__ void k_agg1(const unsigned short* __restrict__ Cl,
                       const unsigned short* __restrict__ Cr,
                       const int* __restrict__ off, const int* __restrict__ csr,
                       unsigned short* __restrict__ h, int nNodes) {
  int node = blockIdx.x * 4 + (threadIdx.x >> 6);
  if (node >= nNodes) return;
  const int l = threadIdx.x & 63;
  const int half = l >> 5, li = l & 31;
  const size_t colb = (size_t)li * 8;
  int s = off[node], e = off[node + 1];
  float a[8] = {};
  agg_sum(Cl, csr, s, e, half, colb, a);
  if (half == 0) {
    float inv = 1.0f / fmaxf((float)(e - s), 1.0f);
    bf16x8 xr = *(const bf16x8*)&Cr[(size_t)node * HID_DIM + colb];   // includes b1
    bf16x8 o;
#pragma unroll
    for (int c = 0; c < 8; ++c)
      o[c] = (short)f2bf(fmaxf(a[c] * inv + bf2f((unsigned short)xr[c]), 0.0f));
    *(bf16x8*)&h[(size_t)node * HID_DIM + colb] = o;
  }
}

__global__ void k_agg2(const unsigned short* __restrict__ hsrc,
                       const int* __restrict__ off, const int* __restrict__ csr,
                       unsigned short* __restrict__ mean2, int nNodes) {
  int node = blockIdx.x * 4 + (threadIdx.x >> 6);
  if (node >= nNodes) return;
  const int l = threadIdx.x & 63;
  const int half = l >> 5, li = l & 31;
  const size_t colb = (size_t)li * 8;
  int s = off[node], e = off[node + 1];
  float a[8] = {};
  agg_sum(hsrc, csr, s, e, half, colb, a);
  if (half == 0) {
    float inv = 1.0f / fmaxf((float)(e - s), 1.0f);
    bf16x8 o;
#pragma unroll
    for (int c = 0; c < 8; ++c) o[c] = (short)f2bf(a[c] * inv);
    *(bf16x8*)&mean2[(size_t)node * HID_DIM + colb] = o;
  }
}

extern "C" void kernel_launch(void* const* d_in, const int* in_sizes, int n_in,
                              void* d_out, int out_size, void* d_ws, size_t ws_size,
                              hipStream_t stream) {
  const float* x   = (const float*)d_in[0];
  const void*  ei  = d_in[1];
  const float* w1l = (const float*)d_in[2];
  const float* w1r = (const float*)d_in[3];
  const float* b1  = (const float*)d_in[4];
  const float* w2l = (const float*)d_in[5];
  const float* w2r = (const float*)d_in[6];
  const float* b2  = (const float*)d_in[7];
  float* out = (float*)d_out;

  const int nN   = in_sizes[0] / IN_DIM;         // 50000
  const int nE   = in_sizes[1] / 2;              // 800000
  const int Mpad = (nN + 127) & ~127;            // 50048
  const int padN = (nN + 1023) & ~1023;          // 50176 (scan granularity)

  char* ws = (char*)d_ws;
  size_t o = 0;
  auto alloc = [&](size_t bytes) {
    char* p = ws + o;
    o += (bytes + 255) & ~(size_t)255;
    return p;
  };
  unsigned short* W1c   = (unsigned short*)alloc((size_t)2 * HID_DIM * IN_DIM * 2);
  unsigned short* W2c   = (unsigned short*)alloc((size_t)OUT_N * 2 * HID_DIM * 2);
  unsigned short* Cl    = (unsigned short*)alloc((size_t)Mpad * HID_DIM * 2);
  unsigned short* Cr    = (unsigned short*)alloc((size_t)Mpad * HID_DIM * 2);
  unsigned short* hbuf  = (unsigned short*)alloc((size_t)Mpad * HID_DIM * 2);
  unsigned short* mean2 = (unsigned short*)alloc((size_t)Mpad * HID_DIM * 2);
  int* deg    = (int*)alloc((size_t)padN * 4);         // zero-padded for int4 scan
  int* offs   = (int*)alloc((size_t)padN * 4);         // off[nN]=nE lands in pad region
  int* cursor = (int*)alloc((size_t)padN * 4);
  int* csr    = (int*)alloc((size_t)nE * 4);
  int* flag   = (int*)alloc(256);

  hipMemsetAsync(deg, 0, (size_t)padN * 4, stream);
  // pad rows of hbuf / mean2 stay 0xAA poison: decodes to ~1e-13 bf16, flows
  // only into pad rows of out-guarded stores -> never observed.  Cl/Cr pad
  // rows hold dup-of-last-row values (clamped A reads) -> never read (csr
  // indices < nN, agg node < nN).

  const int nEb   = (nE + 255) / 256;
  const int ngemm = 4 * (Mpad / 128);            // 1564

  k_pre<<<769 + nEb, 256, 0, stream>>>((const unsigned int*)ei, ei, flag,
                                       w1l, w1r, W1c, w2l, w2r, W2c, nE, deg);
  k_scan1<<<1, 1024, 0, stream>>>(deg, offs, cursor, padN / 4);
  k_g1f<<<ngemm + nEb, 256, 0, stream>>>(x, W1c, Cl, Cr, b1, nN - 1, ngemm,
                                         ei, nE, flag, cursor, csr);
  k_agg1<<<(nN + 3) / 4, 256, 0, stream>>>(Cl, Cr, offs, csr, hbuf, nN);
  k_agg2<<<(nN + 3) / 4, 256, 0, stream>>>(hbuf, offs, csr, mean2, nN);
  dim3 g2(512 / 128, Mpad / 128);
  k_gemm2<<<g2, 256, 0, stream>>>(mean2, hbuf, W2c, out, b2, nN);
}

// Round 5
// 684.066 us; speedup vs baseline: 1.0019x; 1.0019x over previous
//
#include <hip/hip_runtime.h>

// GraphSAGE 2-layer encoder, MI355X (gfx950).  Round 7.
// vs R6 (FAILED: fp32-LDS A-tile -> 24.5KB LDS, occ 20%, 9.6M bank conflicts,
// 230us): revert gemm1 to the R4 known-good bf16 path — xbf precomputed in
// k_pre (307MB streaming, overlaps deg atomics), A and B both staged via
// linear global_load_lds (16KB LDS, ~29% occ).  KEEP the later structural
// wins: single-block scan, csr-fill fused into gemm1's dispatch, 1D grid +
// bijective XCD swizzle, 8/4/2/1 agg cascade.
//   GEMM1: Cl = x@w1_l^T ; Cr = x@w1_r^T + b1          (bf16, [Mpad,256] each)
//   agg1 : h[n] = relu(mean(Cl[src]) + Cr[n])          (bf16 [Mpad,256])
//   agg2 : mean2[n] = mean(h[src])                     (bf16 [Mpad,256])
//   GEMM2: out = [mean2|h] @ [w2_l|w2_r]^T + b2        (fp32 [nN,512])

#define IN_DIM  1024
#define HID_DIM 256
#define OUT_N   512

typedef __attribute__((ext_vector_type(8))) short bf16x8;
typedef __attribute__((ext_vector_type(4))) float f32x4;

static __device__ __forceinline__ unsigned short f2bf(float f) {
  unsigned int u = __float_as_uint(f);
  u += 0x7fffu + ((u >> 16) & 1u);
  return (unsigned short)(u >> 16);
}
static __device__ __forceinline__ float bf2f(unsigned short b) {
  return __uint_as_float(((unsigned int)b) << 16);
}

static __device__ __forceinline__ int load_idx(const void* ei, long long pos, int is64) {
  if (is64) return (int)((const long long*)ei)[pos];
  return ((const int*)ei)[pos];
}

// ---------- fused: dtype detect + weight cvt + x cvt + degree count ----------
// block 0: detect->flag; [1,513): w1cat; [513,769): w2cat;
// [769, 769+nxb): x->bf16; [769+nxb, 769+nxb+nEb): degree atomics.
__global__ void k_pre(const unsigned int* __restrict__ eiu, const void* __restrict__ ei,
                      int* __restrict__ flag,
                      const float* __restrict__ w1l, const float* __restrict__ w1r,
                      unsigned short* __restrict__ W1c,
                      const float* __restrict__ w2l, const float* __restrict__ w2r,
                      unsigned short* __restrict__ W2c,
                      const float* __restrict__ x, unsigned short* __restrict__ xbf,
                      int n4, int nxb, int nE, int* __restrict__ deg) {
  int b = blockIdx.x;
  if (b == 0) {
    if (threadIdx.x < 64) {
      unsigned int v = eiu[2 * threadIdx.x + 1];
      unsigned long long m = __ballot(v == 0u);
      if (threadIdx.x == 0) *flag = (m == ~0ull) ? 1 : 0;
    }
    return;
  }
  if (b < 513) {                      // W1cat[n][k], n<256 -> w1_l else w1_r; K=1024
    int i = (b - 1) * 256 + threadIdx.x;
    int base = i * 4;
    int n = base / IN_DIM, k = base % IN_DIM;
    const float* s = (n < HID_DIM) ? &w1l[(size_t)n * IN_DIM + k]
                                   : &w1r[(size_t)(n - HID_DIM) * IN_DIM + k];
    float4 v = *(const float4*)s;
    ushort4 o = { f2bf(v.x), f2bf(v.y), f2bf(v.z), f2bf(v.w) };
    *(ushort4*)&W1c[base] = o;
    return;
  }
  if (b < 769) {                      // W2cat[n][k], k<256 -> w2_l else w2_r; K=512
    int i = (b - 513) * 256 + threadIdx.x;
    int base = i * 4;
    int n = base >> 9, k = base & 511;
    const float* s = (k < HID_DIM) ? &w2l[(size_t)n * HID_DIM + k]
                                   : &w2r[(size_t)n * HID_DIM + (k - HID_DIM)];
    float4 v = *(const float4*)s;
    ushort4 o = { f2bf(v.x), f2bf(v.y), f2bf(v.z), f2bf(v.w) };
    *(ushort4*)&W2c[base] = o;
    return;
  }
  if (b < 769 + nxb) {                // x -> bf16
    int i = (b - 769) * 256 + threadIdx.x;
    if (i >= n4) return;
    float4 v = ((const float4*)x)[i];
    ushort4 o = { f2bf(v.x), f2bf(v.y), f2bf(v.z), f2bf(v.w) };
    ((ushort4*)xbf)[i] = o;
    return;
  }
  // degree count (per-block dtype detect: no dependency on block 0)
  __shared__ int s_is64;
  if (threadIdx.x < 64) {
    unsigned int v = eiu[2 * threadIdx.x + 1];
    unsigned long long m = __ballot(v == 0u);
    if (threadIdx.x == 0) s_is64 = (m == ~0ull) ? 1 : 0;
  }
  __syncthreads();
  int e = (b - 769 - nxb) * 256 + threadIdx.x;
  if (e < nE) {
    int d = load_idx(ei, (long long)nE + e, s_is64);
    atomicAdd(&deg[d], 1);
  }
}

// ---------- single-block exclusive scan: deg[padN] -> off[], cursor[] ----------
__global__ __launch_bounds__(1024) void k_scan1(const int* __restrict__ deg,
                                                int* __restrict__ off,
                                                int* __restrict__ cursor, int n4q) {
  const int t = threadIdx.x;
  const int CH = (n4q + 1023) >> 10;    // int4s per thread (13 at padN=50176)
  const int i0 = t * CH;
  int tsum = 0;
  for (int i = 0; i < CH; ++i) {
    int idx = i0 + i;
    if (idx < n4q) {
      int4 d = ((const int4*)deg)[idx];
      tsum += d.x + d.y + d.z + d.w;
    }
  }
  __shared__ int s[1024];
  s[t] = tsum;
  __syncthreads();
  for (int d = 1; d < 1024; d <<= 1) {
    int u = (t >= d) ? s[t - d] : 0;
    __syncthreads();
    s[t] += u;
    __syncthreads();
  }
  int run = (t == 0) ? 0 : s[t - 1];
  for (int i = 0; i < CH; ++i) {
    int idx = i0 + i;
    if (idx < n4q) {
      int4 d = ((const int4*)deg)[idx];
      int4 o;
      o.x = run;
      o.y = run + d.x;
      o.z = o.y + d.y;
      o.w = o.z + d.z;
      run = o.w + d.w;
      ((int4*)off)[idx] = o;
      ((int4*)cursor)[idx] = o;
    }
  }
}

// ---------- GEMM helpers ----------
static __device__ __forceinline__ void load_lds16(const void* g, void* lds) {
  __builtin_amdgcn_global_load_lds(
      (const __attribute__((address_space(1))) unsigned int*)g,
      (__attribute__((address_space(3))) unsigned int*)lds, 16, 0, 0);
}

// bijective XCD-chunk swizzle (m204): consecutive logical tiles land on one XCD
static __device__ __forceinline__ int xcd_swz(int orig, int nwg) {
  const int q = nwg >> 3, r = nwg & 7;
  const int xcd = orig & 7, rk = orig >> 3;
  return (xcd < r) ? xcd * (q + 1) + rk : r * (q + 1) + (xcd - r) * q + rk;
}

// ---------- fused GEMM1 + csr fill ----------
// blocks [0, ngemm): gemm1 tiles (1D, wg>>2 = m-tile, wg&3 = n-tile);
// blocks [ngemm, ...): csr fill (independent of gemm1; consumer agg1 is the
// next dispatch on the stream).  A = xbf (bf16, Mpad rows), m97-style
// linear global_load_lds for both operands (R4 known-good).
__global__ __launch_bounds__(256) void k_g1f(const unsigned short* __restrict__ A,
                                             const unsigned short* __restrict__ B,
                                             unsigned short* __restrict__ Cl,
                                             unsigned short* __restrict__ Cr,
                                             const float* __restrict__ b1,
                                             int ngemm,
                                             const void* __restrict__ ei, int nE,
                                             const int* __restrict__ flag,
                                             int* __restrict__ cursor,
                                             int* __restrict__ csr) {
  if ((int)blockIdx.x >= ngemm) {     // ---- csr fill path ----
    int e = ((int)blockIdx.x - ngemm) * 256 + threadIdx.x;
    if (e < nE) {
      int is64 = *flag;
      int s = load_idx(ei, e, is64);
      int d = load_idx(ei, (long long)nE + e, is64);
      int p = atomicAdd(&cursor[d], 1);
      csr[p] = s;
    }
    return;
  }
  __shared__ unsigned short As[128 * 32];
  __shared__ unsigned short Bs[128 * 32];
  const int tid = threadIdx.x;
  const int w = tid >> 6, l = tid & 63;
  const int wm = w >> 1, wn = w & 1;
  const int quad = l >> 4, lane16 = l & 15;
  const int wg = xcd_swz(blockIdx.x, ngemm);
  const int m0 = (wg >> 2) * 128;
  const int n0 = (wg & 3) * 128;

  f32x4 acc[4][4] = {};
  for (int k0 = 0; k0 < IN_DIM; k0 += 32) {
#pragma unroll
    for (int c = 0; c < 2; ++c) {
      const int flat = ((w * 2 + c) << 10);
      const int fb = flat + l * 16;
      const int row = fb >> 6;
      const int cb = fb & 63;
      load_lds16(A + (size_t)(m0 + row) * IN_DIM + (k0 + (cb >> 1)), (char*)As + flat);
      load_lds16(B + (size_t)(n0 + row) * IN_DIM + (k0 + (cb >> 1)), (char*)Bs + flat);
    }
    __syncthreads();
    bf16x8 af[4], bfr[4];
#pragma unroll
    for (int i = 0; i < 4; ++i)
      af[i] = *(const bf16x8*)&As[(wm * 64 + i * 16 + lane16) * 32 + quad * 8];
#pragma unroll
    for (int j = 0; j < 4; ++j)
      bfr[j] = *(const bf16x8*)&Bs[(wn * 64 + j * 16 + lane16) * 32 + quad * 8];
#pragma unroll
    for (int i = 0; i < 4; ++i)
#pragma unroll
      for (int j = 0; j < 4; ++j)
        acc[i][j] = __builtin_amdgcn_mfma_f32_16x16x32_bf16(af[i], bfr[j], acc[i][j], 0, 0, 0);
    __syncthreads();
  }

  const bool right = (n0 >= 256);
  unsigned short* Cb = right ? Cr : Cl;
  const int nc0 = n0 - (right ? 256 : 0);
#pragma unroll
  for (int i = 0; i < 4; ++i) {
    const int rbase = m0 + wm * 64 + i * 16 + quad * 4;
#pragma unroll
    for (int j = 0; j < 4; ++j) {
      const int col = nc0 + wn * 64 + j * 16 + lane16;
      const float bv = right ? b1[col] : 0.0f;
#pragma unroll
      for (int r = 0; r < 4; ++r)
        Cb[(size_t)(rbase + r) * HID_DIM + col] = f2bf(acc[i][j][r] + bv);
    }
  }
}

// GEMM2: A k<256 from Am (mean2), k>=256 from Ah (h); B=W2c[512,512]; fp32 out + b2
__global__ __launch_bounds__(256) void k_gemm2(const unsigned short* __restrict__ Am,
                                               const unsigned short* __restrict__ Ah,
                                               const unsigned short* __restrict__ B,
                                               float* __restrict__ out,
                                               const float* __restrict__ b2, int Mstore) {
  __shared__ unsigned short As[128 * 32];
  __shared__ unsigned short Bs[128 * 32];
  const int tid = threadIdx.x;
  const int w = tid >> 6, l = tid & 63;
  const int wm = w >> 1, wn = w & 1;
  const int quad = l >> 4, lane16 = l & 15;
  const int nwg = gridDim.x * gridDim.y;
  const int wg = xcd_swz(blockIdx.y * gridDim.x + blockIdx.x, nwg);
  const int m0 = (wg / gridDim.x) * 128;
  const int n0 = (wg % gridDim.x) * 128;

  f32x4 acc[4][4] = {};
  for (int k0 = 0; k0 < 2 * HID_DIM; k0 += 32) {
    const unsigned short* Abase = (k0 < HID_DIM) ? Am + k0 : Ah + (k0 - HID_DIM);
#pragma unroll
    for (int c = 0; c < 2; ++c) {
      const int flat = ((w * 2 + c) << 10);
      const int fb = flat + l * 16;
      const int row = fb >> 6;
      const int cb = fb & 63;
      load_lds16(Abase + (size_t)(m0 + row) * HID_DIM + (cb >> 1), (char*)As + flat);
      load_lds16(B + (size_t)(n0 + row) * (2 * HID_DIM) + (k0 + (cb >> 1)), (char*)Bs + flat);
    }
    __syncthreads();
    bf16x8 af[4], bfr[4];
#pragma unroll
    for (int i = 0; i < 4; ++i)
      af[i] = *(const bf16x8*)&As[(wm * 64 + i * 16 + lane16) * 32 + quad * 8];
#pragma unroll
    for (int j = 0; j < 4; ++j)
      bfr[j] = *(const bf16x8*)&Bs[(wn * 64 + j * 16 + lane16) * 32 + quad * 8];
#pragma unroll
    for (int i = 0; i < 4; ++i)
#pragma unroll
      for (int j = 0; j < 4; ++j)
        acc[i][j] = __builtin_amdgcn_mfma_f32_16x16x32_bf16(af[i], bfr[j], acc[i][j], 0, 0, 0);
    __syncthreads();
  }

#pragma unroll
  for (int i = 0; i < 4; ++i) {
    const int rbase = m0 + wm * 64 + i * 16 + quad * 4;
#pragma unroll
    for (int j = 0; j < 4; ++j) {
      const int col = n0 + wn * 64 + j * 16 + lane16;
      const float bv = b2[col];
#pragma unroll
      for (int r = 0; r < 4; ++r) {
        const int rowi = rbase + r;
        if (rowi < Mstore) out[(size_t)rowi * OUT_N + col] = acc[i][j][r] + bv;
      }
    }
  }
}

// ---------- aggregations: 1 wave/node, 16B/lane, 8/4/2/1-pair batch cascade ----------
template <int NB>
static __device__ __forceinline__ void gatherN(const unsigned short* __restrict__ src,
                                               const int* __restrict__ csr, int ib,
                                               size_t colb, float* a) {
  bf16x8 v[NB];
#pragma unroll
  for (int u = 0; u < NB; ++u) {
    int r = csr[ib + 2 * u];
    v[u] = *(const bf16x8*)&src[(size_t)r * HID_DIM + colb];
  }
#pragma unroll
  for (int u = 0; u < NB; ++u)
#pragma unroll
    for (int c = 0; c < 8; ++c) a[c] += bf2f((unsigned short)v[u][c]);
}

static __device__ __forceinline__ void agg_sum(const unsigned short* __restrict__ src,
                                               const int* __restrict__ csr,
                                               int s, int e, int half, size_t colb,
                                               float* a) {
  const int cnt = e - s;
  const int P = cnt >> 1;
  const int ib0 = s + half;
  int k = 0;
  for (; k + 8 <= P; k += 8) gatherN<8>(src, csr, ib0 + 2 * k, colb, a);
  if (k + 4 <= P) { gatherN<4>(src, csr, ib0 + 2 * k, colb, a); k += 4; }
  if (k + 2 <= P) { gatherN<2>(src, csr, ib0 + 2 * k, colb, a); k += 2; }
  if (k < P)      { gatherN<1>(src, csr, ib0 + 2 * k, colb, a); }
  if ((cnt & 1) && half == 0) {
    bf16x8 v = *(const bf16x8*)&src[(size_t)csr[e - 1] * HID_DIM + colb];
#pragma unroll
    for (int c = 0; c < 8; ++c) a[c] += bf2f((unsigned short)v[c]);
  }
#pragma unroll
  for (int c = 0; c < 8; ++c) a[c] += __shfl_xor(a[c], 32);
}

__global__ void k_agg1(const unsigned short* __restrict__ Cl,
                       const unsigned short* __restrict__ Cr,
                       const int* __restrict__ off, const int* __restrict__ csr,
                       unsigned short* __restrict__ h, int nNodes) {
  int node = blockIdx.x * 4 + (threadIdx.x >> 6);
  if (node >= nNodes) return;
  const int l = threadIdx.x & 63;
  const int half = l >> 5, li = l & 31;
  const size_t colb = (size_t)li * 8;
  int s = off[node], e = off[node + 1];
  float a[8] = {};
  agg_sum(Cl, csr, s, e, half, colb, a);
  if (half == 0) {
    float inv = 1.0f / fmaxf((float)(e - s), 1.0f);
    bf16x8 xr = *(const bf16x8*)&Cr[(size_t)node * HID_DIM + colb];   // includes b1
    bf16x8 o;
#pragma unroll
    for (int c = 0; c < 8; ++c)
      o[c] = (short)f2bf(fmaxf(a[c] * inv + bf2f((unsigned short)xr[c]), 0.0f));
    *(bf16x8*)&h[(size_t)node * HID_DIM + colb] = o;
  }
}

__global__ void k_agg2(const unsigned short* __restrict__ hsrc,
                       const int* __restrict__ off, const int* __restrict__ csr,
                       unsigned short* __restrict__ mean2, int nNodes) {
  int node = blockIdx.x * 4 + (threadIdx.x >> 6);
  if (node >= nNodes) return;
  const int l = threadIdx.x & 63;
  const int half = l >> 5, li = l & 31;
  const size_t colb = (size_t)li * 8;
  int s = off[node], e = off[node + 1];
  float a[8] = {};
  agg_sum(hsrc, csr, s, e, half, colb, a);
  if (half == 0) {
    float inv = 1.0f / fmaxf((float)(e - s), 1.0f);
    bf16x8 o;
#pragma unroll
    for (int c = 0; c < 8; ++c) o[c] = (short)f2bf(a[c] * inv);
    *(bf16x8*)&mean2[(size_t)node * HID_DIM + colb] = o;
  }
}

extern "C" void kernel_launch(void* const* d_in, const int* in_sizes, int n_in,
                              void* d_out, int out_size, void* d_ws, size_t ws_size,
                              hipStream_t stream) {
  const float* x   = (const float*)d_in[0];
  const void*  ei  = d_in[1];
  const float* w1l = (const float*)d_in[2];
  const float* w1r = (const float*)d_in[3];
  const float* b1  = (const float*)d_in[4];
  const float* w2l = (const float*)d_in[5];
  const float* w2r = (const float*)d_in[6];
  const float* b2  = (const float*)d_in[7];
  float* out = (float*)d_out;

  const int nN   = in_sizes[0] / IN_DIM;         // 50000
  const int nE   = in_sizes[1] / 2;              // 800000
  const int Mpad = (nN + 127) & ~127;            // 50048
  const int padN = (nN + 1023) & ~1023;          // 50176 (scan granularity)

  char* ws = (char*)d_ws;
  size_t o = 0;
  auto alloc = [&](size_t bytes) {
    char* p = ws + o;
    o += (bytes + 255) & ~(size_t)255;
    return p;
  };
  unsigned short* xbf   = (unsigned short*)alloc((size_t)Mpad * IN_DIM * 2);
  unsigned short* W1c   = (unsigned short*)alloc((size_t)2 * HID_DIM * IN_DIM * 2);
  unsigned short* W2c   = (unsigned short*)alloc((size_t)OUT_N * 2 * HID_DIM * 2);
  unsigned short* Cl    = (unsigned short*)alloc((size_t)Mpad * HID_DIM * 2);
  unsigned short* Cr    = (unsigned short*)alloc((size_t)Mpad * HID_DIM * 2);
  unsigned short* hbuf  = (unsigned short*)alloc((size_t)Mpad * HID_DIM * 2);
  unsigned short* mean2 = (unsigned short*)alloc((size_t)Mpad * HID_DIM * 2);
  int* deg    = (int*)alloc((size_t)padN * 4);         // zero-padded for int4 scan
  int* offs   = (int*)alloc((size_t)padN * 4);         // off[nN]=nE lands in pad region
  int* cursor = (int*)alloc((size_t)padN * 4);
  int* csr    = (int*)alloc((size_t)nE * 4);
  int* flag   = (int*)alloc(256);

  hipMemsetAsync(deg, 0, (size_t)padN * 4, stream);
  // pad rows of xbf / hbuf / mean2 stay 0xAA poison: decodes to ~1e-13 bf16,
  // flows only into pad rows of Cl/Cr/out-guarded stores -> never observed.

  const int n4  = nN * IN_DIM / 4;
  const int nxb = (n4 + 255) / 256;
  const int nEb = (nE + 255) / 256;
  const int ngemm = 4 * (Mpad / 128);            // 1564

  k_pre<<<769 + nxb + nEb, 256, 0, stream>>>((const unsigned int*)ei, ei, flag,
                                             w1l, w1r, W1c, w2l, w2r, W2c,
                                             x, xbf, n4, nxb, nE, deg);
  k_scan1<<<1, 1024, 0, stream>>>(deg, offs, cursor, padN / 4);
  k_g1f<<<ngemm + nEb, 256, 0, stream>>>(xbf, W1c, Cl, Cr, b1, ngemm,
                                         ei, nE, flag, cursor, csr);
  k_agg1<<<(nN + 3) / 4, 256, 0, stream>>>(Cl, Cr, offs, csr, hbuf, nN);
  k_agg2<<<(nN + 3) / 4, 256, 0, stream>>>(hbuf, offs, csr, mean2, nN);
  dim3 g2(512 / 128, Mpad / 128);
  k_gemm2<<<g2, 256, 0, stream>>>(mean2, hbuf, W2c, out, b2, nN);
}

// Round 6
// 675.178 us; speedup vs baseline: 1.0151x; 1.0132x over previous
//
#include <hip/hip_runtime.h>

// GraphSAGE 2-layer encoder, MI355X (gfx950).  Round 8.
// vs R7: (1) scan reverted to the R4 3-kernel parallel chain (single-block
// k_scan1 was ~15-20us slower); (2) k_g1f gemm path and k_gemm2 get 2-phase
// double-buffered LDS staging (T3-minimum): STAGE(t+1) issued before
// compute(t), ONE barrier per K-step — attacks the measured latency-bound
// profile (MfmaUtil 14%, VALUBusy 8.6%, HBM 15%: all idle = barrier drain).
//   GEMM1: Cl = x@w1_l^T ; Cr = x@w1_r^T + b1          (bf16, [Mpad,256] each)
//   agg1 : h[n] = relu(mean(Cl[src]) + Cr[n])          (bf16 [Mpad,256])
//   agg2 : mean2[n] = mean(h[src])                     (bf16 [Mpad,256])
//   GEMM2: out = [mean2|h] @ [w2_l|w2_r]^T + b2        (fp32 [nN,512])

#define IN_DIM  1024
#define HID_DIM 256
#define OUT_N   512

typedef __attribute__((ext_vector_type(8))) short bf16x8;
typedef __attribute__((ext_vector_type(4))) float f32x4;

static __device__ __forceinline__ unsigned short f2bf(float f) {
  unsigned int u = __float_as_uint(f);
  u += 0x7fffu + ((u >> 16) & 1u);
  return (unsigned short)(u >> 16);
}
static __device__ __forceinline__ float bf2f(unsigned short b) {
  return __uint_as_float(((unsigned int)b) << 16);
}

static __device__ __forceinline__ int load_idx(const void* ei, long long pos, int is64) {
  if (is64) return (int)((const long long*)ei)[pos];
  return ((const int*)ei)[pos];
}

// ---------- fused: dtype detect + weight cvt + x cvt + degree count ----------
__global__ void k_pre(const unsigned int* __restrict__ eiu, const void* __restrict__ ei,
                      int* __restrict__ flag,
                      const float* __restrict__ w1l, const float* __restrict__ w1r,
                      unsigned short* __restrict__ W1c,
                      const float* __restrict__ w2l, const float* __restrict__ w2r,
                      unsigned short* __restrict__ W2c,
                      const float* __restrict__ x, unsigned short* __restrict__ xbf,
                      int n4, int nxb, int nE, int* __restrict__ deg) {
  int b = blockIdx.x;
  if (b == 0) {
    if (threadIdx.x < 64) {
      unsigned int v = eiu[2 * threadIdx.x + 1];
      unsigned long long m = __ballot(v == 0u);
      if (threadIdx.x == 0) *flag = (m == ~0ull) ? 1 : 0;
    }
    return;
  }
  if (b < 513) {                      // W1cat[n][k], n<256 -> w1_l else w1_r; K=1024
    int i = (b - 1) * 256 + threadIdx.x;
    int base = i * 4;
    int n = base / IN_DIM, k = base % IN_DIM;
    const float* s = (n < HID_DIM) ? &w1l[(size_t)n * IN_DIM + k]
                                   : &w1r[(size_t)(n - HID_DIM) * IN_DIM + k];
    float4 v = *(const float4*)s;
    ushort4 o = { f2bf(v.x), f2bf(v.y), f2bf(v.z), f2bf(v.w) };
    *(ushort4*)&W1c[base] = o;
    return;
  }
  if (b < 769) {                      // W2cat[n][k], k<256 -> w2_l else w2_r; K=512
    int i = (b - 513) * 256 + threadIdx.x;
    int base = i * 4;
    int n = base >> 9, k = base & 511;
    const float* s = (k < HID_DIM) ? &w2l[(size_t)n * HID_DIM + k]
                                   : &w2r[(size_t)n * HID_DIM + (k - HID_DIM)];
    float4 v = *(const float4*)s;
    ushort4 o = { f2bf(v.x), f2bf(v.y), f2bf(v.z), f2bf(v.w) };
    *(ushort4*)&W2c[base] = o;
    return;
  }
  if (b < 769 + nxb) {                // x -> bf16
    int i = (b - 769) * 256 + threadIdx.x;
    if (i >= n4) return;
    float4 v = ((const float4*)x)[i];
    ushort4 o = { f2bf(v.x), f2bf(v.y), f2bf(v.z), f2bf(v.w) };
    ((ushort4*)xbf)[i] = o;
    return;
  }
  // degree count (per-block dtype detect: no dependency on block 0)
  __shared__ int s_is64;
  if (threadIdx.x < 64) {
    unsigned int v = eiu[2 * threadIdx.x + 1];
    unsigned long long m = __ballot(v == 0u);
    if (threadIdx.x == 0) s_is64 = (m == ~0ull) ? 1 : 0;
  }
  __syncthreads();
  int e = (b - 769 - nxb) * 256 + threadIdx.x;
  if (e < nE) {
    int d = load_idx(ei, (long long)nE + e, s_is64);
    atomicAdd(&deg[d], 1);
  }
}

// ---------- CSR build: 3-kernel parallel scan (R4 proven) ----------
__global__ void k_bsum(const int* __restrict__ deg, int* __restrict__ bsum) {
  int t = threadIdx.x;
  int4 d4 = ((const int4*)(deg + (size_t)blockIdx.x * 1024))[t];
  int v = d4.x + d4.y + d4.z + d4.w;
#pragma unroll
  for (int d = 1; d < 64; d <<= 1) v += __shfl_xor(v, d);
  __shared__ int ws[4];
  if ((t & 63) == 0) ws[t >> 6] = v;
  __syncthreads();
  if (t == 0) bsum[blockIdx.x] = ws[0] + ws[1] + ws[2] + ws[3];
}

__global__ __launch_bounds__(1024) void k_bscan(int* __restrict__ bsum, int nb) {
  __shared__ int s[1024];
  int t = threadIdx.x;
  s[t] = (t < nb) ? bsum[t] : 0;
  __syncthreads();
  for (int d = 1; d < 1024; d <<= 1) {
    int v = (t >= d) ? s[t - d] : 0;
    __syncthreads();
    s[t] += v;
    __syncthreads();
  }
  if (t < nb) bsum[t] = s[t];
}

__global__ __launch_bounds__(256) void k_offsets(const int* __restrict__ deg,
                                                 const int* __restrict__ bsumInc,
                                                 int* __restrict__ off,
                                                 int* __restrict__ cursor) {
  const int t = threadIdx.x;
  const int l = t & 63, w = t >> 6;
  const size_t base = (size_t)blockIdx.x * 1024;
  int4 d4 = ((const int4*)(deg + base))[t];
  int tsum = d4.x + d4.y + d4.z + d4.w;
  int incl = tsum;
#pragma unroll
  for (int d = 1; d < 64; d <<= 1) {
    int u = __shfl_up(incl, d);
    if (l >= d) incl += u;
  }
  __shared__ int wt[4];
  if (l == 63) wt[w] = incl;
  __syncthreads();
  int wpre = 0;
  for (int i = 0; i < w; ++i) wpre += wt[i];
  int bpre = (blockIdx.x == 0) ? 0 : bsumInc[blockIdx.x - 1];
  int excl = bpre + wpre + incl - tsum;
  int4 o;
  o.x = excl;
  o.y = excl + d4.x;
  o.z = o.y + d4.y;
  o.w = o.z + d4.z;
  ((int4*)(off + base))[t] = o;
  ((int4*)(cursor + base))[t] = o;
}

// ---------- GEMM helpers ----------
static __device__ __forceinline__ void load_lds16(const void* g, void* lds) {
  __builtin_amdgcn_global_load_lds(
      (const __attribute__((address_space(1))) unsigned int*)g,
      (__attribute__((address_space(3))) unsigned int*)lds, 16, 0, 0);
}

// bijective XCD-chunk swizzle (m204)
static __device__ __forceinline__ int xcd_swz(int orig, int nwg) {
  const int q = nwg >> 3, r = nwg & 7;
  const int xcd = orig & 7, rk = orig >> 3;
  return (xcd < r) ? xcd * (q + 1) + rk : r * (q + 1) + (xcd - r) * q + rk;
}

// ---------- fused GEMM1 + csr fill, 2-phase double-buffered staging ----------
// blocks [0, ngemm): gemm1 tiles; [ngemm, ...): csr fill.
// Per K-step: STAGE(t+1 -> buf^1) issued first (loads in flight), then
// ds_read+MFMA from buf, then ONE __syncthreads (drains vmcnt for t+1's
// stage + lgkm).  buf^1's previous readers finished before the prior
// barrier, so the overwrite is safe.
__global__ __launch_bounds__(256) void k_g1f(const unsigned short* __restrict__ A,
                                             const unsigned short* __restrict__ B,
                                             unsigned short* __restrict__ Cl,
                                             unsigned short* __restrict__ Cr,
                                             const float* __restrict__ b1,
                                             int ngemm,
                                             const void* __restrict__ ei, int nE,
                                             const int* __restrict__ flag,
                                             int* __restrict__ cursor,
                                             int* __restrict__ csr) {
  if ((int)blockIdx.x >= ngemm) {     // ---- csr fill path ----
    int e = ((int)blockIdx.x - ngemm) * 256 + threadIdx.x;
    if (e < nE) {
      int is64 = *flag;
      int s = load_idx(ei, e, is64);
      int d = load_idx(ei, (long long)nE + e, is64);
      int p = atomicAdd(&cursor[d], 1);
      csr[p] = s;
    }
    return;
  }
  __shared__ unsigned short As[2][128 * 32];
  __shared__ unsigned short Bs[2][128 * 32];
  const int tid = threadIdx.x;
  const int w = tid >> 6, l = tid & 63;
  const int wm = w >> 1, wn = w & 1;
  const int quad = l >> 4, lane16 = l & 15;
  const int wg = xcd_swz(blockIdx.x, ngemm);
  const int m0 = (wg >> 2) * 128;
  const int n0 = (wg & 3) * 128;

  // per-thread staging geometry (constant over K)
  const int flat0 = ((w * 2 + 0) << 10), flat1 = ((w * 2 + 1) << 10);
  const int row0 = (flat0 + l * 16) >> 6, cb0 = (flat0 + l * 16) & 63;
  const int row1 = (flat1 + l * 16) >> 6, cb1 = (flat1 + l * 16) & 63;
  const unsigned short* Ar0 = A + (size_t)(m0 + row0) * IN_DIM + (cb0 >> 1);
  const unsigned short* Ar1 = A + (size_t)(m0 + row1) * IN_DIM + (cb1 >> 1);
  const unsigned short* Br0 = B + (size_t)(n0 + row0) * IN_DIM + (cb0 >> 1);
  const unsigned short* Br1 = B + (size_t)(n0 + row1) * IN_DIM + (cb1 >> 1);

  auto STAGE = [&](int k0, int buf) {
    load_lds16(Ar0 + k0, (char*)As[buf] + flat0);
    load_lds16(Br0 + k0, (char*)Bs[buf] + flat0);
    load_lds16(Ar1 + k0, (char*)As[buf] + flat1);
    load_lds16(Br1 + k0, (char*)Bs[buf] + flat1);
  };

  f32x4 acc[4][4] = {};
  STAGE(0, 0);
  __syncthreads();
  int cur = 0;
  for (int k0 = 0; k0 < IN_DIM; k0 += 32) {
    if (k0 + 32 < IN_DIM) STAGE(k0 + 32, cur ^ 1);
    bf16x8 af[4], bfr[4];
#pragma unroll
    for (int i = 0; i < 4; ++i)
      af[i] = *(const bf16x8*)&As[cur][(wm * 64 + i * 16 + lane16) * 32 + quad * 8];
#pragma unroll
    for (int j = 0; j < 4; ++j)
      bfr[j] = *(const bf16x8*)&Bs[cur][(wn * 64 + j * 16 + lane16) * 32 + quad * 8];
#pragma unroll
    for (int i = 0; i < 4; ++i)
#pragma unroll
      for (int j = 0; j < 4; ++j)
        acc[i][j] = __builtin_amdgcn_mfma_f32_16x16x32_bf16(af[i], bfr[j], acc[i][j], 0, 0, 0);
    __syncthreads();                  // drains vmcnt (next stage) + lgkm
    cur ^= 1;
  }

  const bool right = (n0 >= 256);
  unsigned short* Cb = right ? Cr : Cl;
  const int nc0 = n0 - (right ? 256 : 0);
#pragma unroll
  for (int i = 0; i < 4; ++i) {
    const int rbase = m0 + wm * 64 + i * 16 + quad * 4;
#pragma unroll
    for (int j = 0; j < 4; ++j) {
      const int col = nc0 + wn * 64 + j * 16 + lane16;
      const float bv = right ? b1[col] : 0.0f;
#pragma unroll
      for (int r = 0; r < 4; ++r)
        Cb[(size_t)(rbase + r) * HID_DIM + col] = f2bf(acc[i][j][r] + bv);
    }
  }
}

// GEMM2: A k<256 from Am (mean2), k>=256 from Ah (h); 2-phase dbuf staging
__global__ __launch_bounds__(256) void k_gemm2(const unsigned short* __restrict__ Am,
                                               const unsigned short* __restrict__ Ah,
                                               const unsigned short* __restrict__ B,
                                               float* __restrict__ out,
                                               const float* __restrict__ b2, int Mstore) {
  __shared__ unsigned short As[2][128 * 32];
  __shared__ unsigned short Bs[2][128 * 32];
  const int tid = threadIdx.x;
  const int w = tid >> 6, l = tid & 63;
  const int wm = w >> 1, wn = w & 1;
  const int quad = l >> 4, lane16 = l & 15;
  const int nwg = gridDim.x * gridDim.y;
  const int wg = xcd_swz(blockIdx.y * gridDim.x + blockIdx.x, nwg);
  const int m0 = (wg / gridDim.x) * 128;
  const int n0 = (wg % gridDim.x) * 128;

  const int flat0 = ((w * 2 + 0) << 10), flat1 = ((w * 2 + 1) << 10);
  const int row0 = (flat0 + l * 16) >> 6, cb0 = (flat0 + l * 16) & 63;
  const int row1 = (flat1 + l * 16) >> 6, cb1 = (flat1 + l * 16) & 63;

  auto STAGE = [&](int kk, int buf) {
    const unsigned short* Abase = (kk < HID_DIM) ? Am + kk : Ah + (kk - HID_DIM);
    load_lds16(Abase + (size_t)(m0 + row0) * HID_DIM + (cb0 >> 1), (char*)As[buf] + flat0);
    load_lds16(B + (size_t)(n0 + row0) * (2 * HID_DIM) + (kk + (cb0 >> 1)), (char*)Bs[buf] + flat0);
    load_lds16(Abase + (size_t)(m0 + row1) * HID_DIM + (cb1 >> 1), (char*)As[buf] + flat1);
    load_lds16(B + (size_t)(n0 + row1) * (2 * HID_DIM) + (kk + (cb1 >> 1)), (char*)Bs[buf] + flat1);
  };

  f32x4 acc[4][4] = {};
  STAGE(0, 0);
  __syncthreads();
  int cur = 0;
  for (int k0 = 0; k0 < 2 * HID_DIM; k0 += 32) {
    if (k0 + 32 < 2 * HID_DIM) STAGE(k0 + 32, cur ^ 1);
    bf16x8 af[4], bfr[4];
#pragma unroll
    for (int i = 0; i < 4; ++i)
      af[i] = *(const bf16x8*)&As[cur][(wm * 64 + i * 16 + lane16) * 32 + quad * 8];
#pragma unroll
    for (int j = 0; j < 4; ++j)
      bfr[j] = *(const bf16x8*)&Bs[cur][(wn * 64 + j * 16 + lane16) * 32 + quad * 8];
#pragma unroll
    for (int i = 0; i < 4; ++i)
#pragma unroll
      for (int j = 0; j < 4; ++j)
        acc[i][j] = __builtin_amdgcn_mfma_f32_16x16x32_bf16(af[i], bfr[j], acc[i][j], 0, 0, 0);
    __syncthreads();
    cur ^= 1;
  }

#pragma unroll
  for (int i = 0; i < 4; ++i) {
    const int rbase = m0 + wm * 64 + i * 16 + quad * 4;
#pragma unroll
    for (int j = 0; j < 4; ++j) {
      const int col = n0 + wn * 64 + j * 16 + lane16;
      const float bv = b2[col];
#pragma unroll
      for (int r = 0; r < 4; ++r) {
        const int rowi = rbase + r;
        if (rowi < Mstore) out[(size_t)rowi * OUT_N + col] = acc[i][j][r] + bv;
      }
    }
  }
}

// ---------- aggregations: 1 wave/node, 16B/lane, 8/4/2/1-pair batch cascade ----------
template <int NB>
static __device__ __forceinline__ void gatherN(const unsigned short* __restrict__ src,
                                               const int* __restrict__ csr, int ib,
                                               size_t colb, float* a) {
  bf16x8 v[NB];
#pragma unroll
  for (int u = 0; u < NB; ++u) {
    int r = csr[ib + 2 * u];
    v[u] = *(const bf16x8*)&src[(size_t)r * HID_DIM + colb];
  }
#pragma unroll
  for (int u = 0; u < NB; ++u)
#pragma unroll
    for (int c = 0; c < 8; ++c) a[c] += bf2f((unsigned short)v[u][c]);
}

static __device__ __forceinline__ void agg_sum(const unsigned short* __restrict__ src,
                                               const int* __restrict__ csr,
                                               int s, int e, int half, size_t colb,
                                               float* a) {
  const int cnt = e - s;
  const int P = cnt >> 1;
  const int ib0 = s + half;
  int k = 0;
  for (; k + 8 <= P; k += 8) gatherN<8>(src, csr, ib0 + 2 * k, colb, a);
  if (k + 4 <= P) { gatherN<4>(src, csr, ib0 + 2 * k, colb, a); k += 4; }
  if (k + 2 <= P) { gatherN<2>(src, csr, ib0 + 2 * k, colb, a); k += 2; }
  if (k < P)      { gatherN<1>(src, csr, ib0 + 2 * k, colb, a); }
  if ((cnt & 1) && half == 0) {
    bf16x8 v = *(const bf16x8*)&src[(size_t)csr[e - 1] * HID_DIM + colb];
#pragma unroll
    for (int c = 0; c < 8; ++c) a[c] += bf2f((unsigned short)v[c]);
  }
#pragma unroll
  for (int c = 0; c < 8; ++c) a[c] += __shfl_xor(a[c], 32);
}

__global__ void k_agg1(const unsigned short* __restrict__ Cl,
                       const unsigned short* __restrict__ Cr,
                       const int* __restrict__ off, const int* __restrict__ csr,
                       unsigned short* __restrict__ h, int nNodes) {
  int node = blockIdx.x * 4 + (threadIdx.x >> 6);
  if (node >= nNodes) return;
  const int l = threadIdx.x & 63;
  const int half = l >> 5, li = l & 31;
  const size_t colb = (size_t)li * 8;
  int s = off[node], e = off[node + 1];
  float a[8] = {};
  agg_sum(Cl, csr, s, e, half, colb, a);
  if (half == 0) {
    float inv = 1.0f / fmaxf((float)(e - s), 1.0f);
    bf16x8 xr = *(const bf16x8*)&Cr[(size_t)node * HID_DIM + colb];   // includes b1
    bf16x8 o;
#pragma unroll
    for (int c = 0; c < 8; ++c)
      o[c] = (short)f2bf(fmaxf(a[c] * inv + bf2f((unsigned short)xr[c]), 0.0f));
    *(bf16x8*)&h[(size_t)node * HID_DIM + colb] = o;
  }
}

__global__ void k_agg2(const unsigned short* __restrict__ hsrc,
                       const int* __restrict__ off, const int* __restrict__ csr,
                       unsigned short* __restrict__ mean2, int nNodes) {
  int node = blockIdx.x * 4 + (threadIdx.x >> 6);
  if (node >= nNodes) return;
  const int l = threadIdx.x & 63;
  const int half = l >> 5, li = l & 31;
  const size_t colb = (size_t)li * 8;
  int s = off[node], e = off[node + 1];
  float a[8] = {};
  agg_sum(hsrc, csr, s, e, half, colb, a);
  if (half == 0) {
    float inv = 1.0f / fmaxf((float)(e - s), 1.0f);
    bf16x8 o;
#pragma unroll
    for (int c = 0; c < 8; ++c) o[c] = (short)f2bf(a[c] * inv);
    *(bf16x8*)&mean2[(size_t)node * HID_DIM + colb] = o;
  }
}

extern "C" void kernel_launch(void* const* d_in, const int* in_sizes, int n_in,
                              void* d_out, int out_size, void* d_ws, size_t ws_size,
                              hipStream_t stream) {
  const float* x   = (const float*)d_in[0];
  const void*  ei  = d_in[1];
  const float* w1l = (const float*)d_in[2];
  const float* w1r = (const float*)d_in[3];
  const float* b1  = (const float*)d_in[4];
  const float* w2l = (const float*)d_in[5];
  const float* w2r = (const float*)d_in[6];
  const float* b2  = (const float*)d_in[7];
  float* out = (float*)d_out;

  const int nN   = in_sizes[0] / IN_DIM;         // 50000
  const int nE   = in_sizes[1] / 2;              // 800000
  const int Mpad = (nN + 127) & ~127;            // 50048
  const int padN = (nN + 1023) & ~1023;          // 50176 (scan granularity)
  const int nb   = padN >> 10;                   // 49 scan blocks

  char* ws = (char*)d_ws;
  size_t o = 0;
  auto alloc = [&](size_t bytes) {
    char* p = ws + o;
    o += (bytes + 255) & ~(size_t)255;
    return p;
  };
  unsigned short* xbf   = (unsigned short*)alloc((size_t)Mpad * IN_DIM * 2);
  unsigned short* W1c   = (unsigned short*)alloc((size_t)2 * HID_DIM * IN_DIM * 2);
  unsigned short* W2c   = (unsigned short*)alloc((size_t)OUT_N * 2 * HID_DIM * 2);
  unsigned short* Cl    = (unsigned short*)alloc((size_t)Mpad * HID_DIM * 2);
  unsigned short* Cr    = (unsigned short*)alloc((size_t)Mpad * HID_DIM * 2);
  unsigned short* hbuf  = (unsigned short*)alloc((size_t)Mpad * HID_DIM * 2);
  unsigned short* mean2 = (unsigned short*)alloc((size_t)Mpad * HID_DIM * 2);
  int* deg    = (int*)alloc((size_t)padN * 4);         // zero-padded for int4 scan
  int* offs   = (int*)alloc((size_t)padN * 4);         // off[nN]=nE lands in pad region
  int* cursor = (int*)alloc((size_t)padN * 4);
  int* bsum   = (int*)alloc((size_t)1024 * 4);
  int* csr    = (int*)alloc((size_t)nE * 4);
  int* flag   = (int*)alloc(256);

  hipMemsetAsync(deg, 0, (size_t)padN * 4, stream);
  // pad rows of xbf / hbuf / mean2 stay 0xAA poison: decodes to ~1e-13 bf16,
  // flows only into pad rows of Cl/Cr/out-guarded stores -> never observed.

  const int n4  = nN * IN_DIM / 4;
  const int nxb = (n4 + 255) / 256;
  const int nEb = (nE + 255) / 256;
  const int ngemm = 4 * (Mpad / 128);            // 1564

  k_pre<<<769 + nxb + nEb, 256, 0, stream>>>((const unsigned int*)ei, ei, flag,
                                             w1l, w1r, W1c, w2l, w2r, W2c,
                                             x, xbf, n4, nxb, nE, deg);
  k_bsum<<<nb, 256, 0, stream>>>(deg, bsum);
  k_bscan<<<1, 1024, 0, stream>>>(bsum, nb);
  k_offsets<<<nb, 256, 0, stream>>>(deg, bsum, offs, cursor);
  k_g1f<<<ngemm + nEb, 256, 0, stream>>>(xbf, W1c, Cl, Cr, b1, ngemm,
                                         ei, nE, flag, cursor, csr);
  k_agg1<<<(nN + 3) / 4, 256, 0, stream>>>(Cl, Cr, offs, csr, hbuf, nN);
  k_agg2<<<(nN + 3) / 4, 256, 0, stream>>>(hbuf, offs, csr, mean2, nN);
  dim3 g2(512 / 128, Mpad / 128);
  k_gemm2<<<g2, 256, 0, stream>>>(mean2, hbuf, W2c, out, b2, nN);
}

// Round 7
// 647.313 us; speedup vs baseline: 1.0588x; 1.0430x over previous
//
#include <hip/hip_runtime.h>

// GraphSAGE 2-layer encoder, MI355X (gfx950).  Round 9.
// vs R8: explicit dbuf REVERTED (measured -15us regression, reproduces m99).
// GEMMs move to BK=64 single-buffer + T2 both-sides XOR swizzle:
//   - 16 K-steps instead of 32 -> half the vmcnt(0)+barrier drains, 8 loads
//     in flight per drain (2x latency amortization);
//   - LDS tile [128][64] bf16 (128B rows): phys 16B-unit = c ^ (row&7),
//     applied on the pre-swizzled per-lane GLOBAL source (global_load_lds
//     writes linearly) and on the ds_read_b128 side -> 2-way (free) instead
//     of the measured 6.4M (8-way) conflicts.
// Scan stays the R4/R8 3-kernel parallel chain.  Fill stays fused in g1f.
//   GEMM1: Cl = x@w1_l^T ; Cr = x@w1_r^T + b1          (bf16, [Mpad,256] each)
//   agg1 : h[n] = relu(mean(Cl[src]) + Cr[n])          (bf16 [Mpad,256])
//   agg2 : mean2[n] = mean(h[src])                     (bf16 [Mpad,256])
//   GEMM2: out = [mean2|h] @ [w2_l|w2_r]^T + b2        (fp32 [nN,512])

#define IN_DIM  1024
#define HID_DIM 256
#define OUT_N   512

typedef __attribute__((ext_vector_type(8))) short bf16x8;
typedef __attribute__((ext_vector_type(4))) float f32x4;

static __device__ __forceinline__ unsigned short f2bf(float f) {
  unsigned int u = __float_as_uint(f);
  u += 0x7fffu + ((u >> 16) & 1u);
  return (unsigned short)(u >> 16);
}
static __device__ __forceinline__ float bf2f(unsigned short b) {
  return __uint_as_float(((unsigned int)b) << 16);
}

static __device__ __forceinline__ int load_idx(const void* ei, long long pos, int is64) {
  if (is64) return (int)((const long long*)ei)[pos];
  return ((const int*)ei)[pos];
}

// ---------- fused: dtype detect + weight cvt + x cvt + degree count ----------
__global__ void k_pre(const unsigned int* __restrict__ eiu, const void* __restrict__ ei,
                      int* __restrict__ flag,
                      const float* __restrict__ w1l, const float* __restrict__ w1r,
                      unsigned short* __restrict__ W1c,
                      const float* __restrict__ w2l, const float* __restrict__ w2r,
                      unsigned short* __restrict__ W2c,
                      const float* __restrict__ x, unsigned short* __restrict__ xbf,
                      int n4, int nxb, int nE, int* __restrict__ deg) {
  int b = blockIdx.x;
  if (b == 0) {
    if (threadIdx.x < 64) {
      unsigned int v = eiu[2 * threadIdx.x + 1];
      unsigned long long m = __ballot(v == 0u);
      if (threadIdx.x == 0) *flag = (m == ~0ull) ? 1 : 0;
    }
    return;
  }
  if (b < 513) {                      // W1cat[n][k], n<256 -> w1_l else w1_r; K=1024
    int i = (b - 1) * 256 + threadIdx.x;
    int base = i * 4;
    int n = base / IN_DIM, k = base % IN_DIM;
    const float* s = (n < HID_DIM) ? &w1l[(size_t)n * IN_DIM + k]
                                   : &w1r[(size_t)(n - HID_DIM) * IN_DIM + k];
    float4 v = *(const float4*)s;
    ushort4 o = { f2bf(v.x), f2bf(v.y), f2bf(v.z), f2bf(v.w) };
    *(ushort4*)&W1c[base] = o;
    return;
  }
  if (b < 769) {                      // W2cat[n][k], k<256 -> w2_l else w2_r; K=512
    int i = (b - 513) * 256 + threadIdx.x;
    int base = i * 4;
    int n = base >> 9, k = base & 511;
    const float* s = (k < HID_DIM) ? &w2l[(size_t)n * HID_DIM + k]
                                   : &w2r[(size_t)n * HID_DIM + (k - HID_DIM)];
    float4 v = *(const float4*)s;
    ushort4 o = { f2bf(v.x), f2bf(v.y), f2bf(v.z), f2bf(v.w) };
    *(ushort4*)&W2c[base] = o;
    return;
  }
  if (b < 769 + nxb) {                // x -> bf16
    int i = (b - 769) * 256 + threadIdx.x;
    if (i >= n4) return;
    float4 v = ((const float4*)x)[i];
    ushort4 o = { f2bf(v.x), f2bf(v.y), f2bf(v.z), f2bf(v.w) };
    ((ushort4*)xbf)[i] = o;
    return;
  }
  // degree count (per-block dtype detect: no dependency on block 0)
  __shared__ int s_is64;
  if (threadIdx.x < 64) {
    unsigned int v = eiu[2 * threadIdx.x + 1];
    unsigned long long m = __ballot(v == 0u);
    if (threadIdx.x == 0) s_is64 = (m == ~0ull) ? 1 : 0;
  }
  __syncthreads();
  int e = (b - 769 - nxb) * 256 + threadIdx.x;
  if (e < nE) {
    int d = load_idx(ei, (long long)nE + e, s_is64);
    atomicAdd(&deg[d], 1);
  }
}

// ---------- CSR build: 3-kernel parallel scan ----------
__global__ void k_bsum(const int* __restrict__ deg, int* __restrict__ bsum) {
  int t = threadIdx.x;
  int4 d4 = ((const int4*)(deg + (size_t)blockIdx.x * 1024))[t];
  int v = d4.x + d4.y + d4.z + d4.w;
#pragma unroll
  for (int d = 1; d < 64; d <<= 1) v += __shfl_xor(v, d);
  __shared__ int ws[4];
  if ((t & 63) == 0) ws[t >> 6] = v;
  __syncthreads();
  if (t == 0) bsum[blockIdx.x] = ws[0] + ws[1] + ws[2] + ws[3];
}

__global__ __launch_bounds__(1024) void k_bscan(int* __restrict__ bsum, int nb) {
  __shared__ int s[1024];
  int t = threadIdx.x;
  s[t] = (t < nb) ? bsum[t] : 0;
  __syncthreads();
  for (int d = 1; d < 1024; d <<= 1) {
    int v = (t >= d) ? s[t - d] : 0;
    __syncthreads();
    s[t] += v;
    __syncthreads();
  }
  if (t < nb) bsum[t] = s[t];
}

__global__ __launch_bounds__(256) void k_offsets(const int* __restrict__ deg,
                                                 const int* __restrict__ bsumInc,
                                                 int* __restrict__ off,
                                                 int* __restrict__ cursor) {
  const int t = threadIdx.x;
  const int l = t & 63, w = t >> 6;
  const size_t base = (size_t)blockIdx.x * 1024;
  int4 d4 = ((const int4*)(deg + base))[t];
  int tsum = d4.x + d4.y + d4.z + d4.w;
  int incl = tsum;
#pragma unroll
  for (int d = 1; d < 64; d <<= 1) {
    int u = __shfl_up(incl, d);
    if (l >= d) incl += u;
  }
  __shared__ int wt[4];
  if (l == 63) wt[w] = incl;
  __syncthreads();
  int wpre = 0;
  for (int i = 0; i < w; ++i) wpre += wt[i];
  int bpre = (blockIdx.x == 0) ? 0 : bsumInc[blockIdx.x - 1];
  int excl = bpre + wpre + incl - tsum;
  int4 o;
  o.x = excl;
  o.y = excl + d4.x;
  o.z = o.y + d4.y;
  o.w = o.z + d4.z;
  ((int4*)(off + base))[t] = o;
  ((int4*)(cursor + base))[t] = o;
}

// ---------- GEMM helpers ----------
static __device__ __forceinline__ void load_lds16(const void* g, void* lds) {
  __builtin_amdgcn_global_load_lds(
      (const __attribute__((address_space(1))) unsigned int*)g,
      (__attribute__((address_space(3))) unsigned int*)lds, 16, 0, 0);
}

// bijective XCD-chunk swizzle (m204)
static __device__ __forceinline__ int xcd_swz(int orig, int nwg) {
  const int q = nwg >> 3, r = nwg & 7;
  const int xcd = orig & 7, rk = orig >> 3;
  return (xcd < r) ? xcd * (q + 1) + rk : r * (q + 1) + (xcd - r) * q + rk;
}

// ---------- fused GEMM1 + csr fill, BK=64 + XOR-swizzled LDS ----------
__global__ __launch_bounds__(256) void k_g1f(const unsigned short* __restrict__ A,
                                             const unsigned short* __restrict__ B,
                                             unsigned short* __restrict__ Cl,
                                             unsigned short* __restrict__ Cr,
                                             const float* __restrict__ b1,
                                             int ngemm,
                                             const void* __restrict__ ei, int nE,
                                             const int* __restrict__ flag,
                                             int* __restrict__ cursor,
                                             int* __restrict__ csr) {
  if ((int)blockIdx.x >= ngemm) {     // ---- csr fill path ----
    int e = ((int)blockIdx.x - ngemm) * 256 + threadIdx.x;
    if (e < nE) {
      int is64 = *flag;
      int s = load_idx(ei, e, is64);
      int d = load_idx(ei, (long long)nE + e, is64);
      int p = atomicAdd(&cursor[d], 1);
      csr[p] = s;
    }
    return;
  }
  __shared__ unsigned short As[128 * 64];   // 16KB, swizzled
  __shared__ unsigned short Bs[128 * 64];   // 16KB, swizzled
  const int tid = threadIdx.x;
  const int w = tid >> 6, l = tid & 63;
  const int wm = w >> 1, wn = w & 1;
  const int quad = l >> 4, lane16 = l & 15;
  const int wg = xcd_swz(blockIdx.x, ngemm);
  const int m0 = (wg >> 2) * 128;
  const int n0 = (wg & 3) * 128;

  // staging sources (constant over K): issue it covers phys units (w*4+it)*64+l
  const unsigned short* asrc[4];
  const unsigned short* bsrc[4];
#pragma unroll
  for (int it = 0; it < 4; ++it) {
    const int p_lin = (w * 4 + it) * 64 + l;
    const int row = p_lin >> 3;
    const int c = (p_lin & 7) ^ (row & 7);
    asrc[it] = A + (size_t)(m0 + row) * IN_DIM + c * 8;
    bsrc[it] = B + (size_t)(n0 + row) * IN_DIM + c * 8;
  }
  int arb[4], brb[4];
#pragma unroll
  for (int i = 0; i < 4; ++i) {
    arb[i] = wm * 64 + i * 16 + lane16;
    brb[i] = wn * 64 + i * 16 + lane16;
  }

  f32x4 acc[4][4] = {};
  for (int k0 = 0; k0 < IN_DIM; k0 += 64) {
#pragma unroll
    for (int it = 0; it < 4; ++it)
      load_lds16(asrc[it] + k0, (char*)As + ((w * 4 + it) << 10));
#pragma unroll
    for (int it = 0; it < 4; ++it)
      load_lds16(bsrc[it] + k0, (char*)Bs + ((w * 4 + it) << 10));
    __syncthreads();
#pragma unroll
    for (int kk = 0; kk < 2; ++kk) {
      bf16x8 af[4], bfr[4];
#pragma unroll
      for (int i = 0; i < 4; ++i) {
        const int r = arb[i];
        af[i] = *(const bf16x8*)((const char*)As + r * 128 +
                                 (((kk * 4 + quad) ^ (r & 7)) << 4));
      }
#pragma unroll
      for (int j = 0; j < 4; ++j) {
        const int r = brb[j];
        bfr[j] = *(const bf16x8*)((const char*)Bs + r * 128 +
                                  (((kk * 4 + quad) ^ (r & 7)) << 4));
      }
#pragma unroll
      for (int i = 0; i < 4; ++i)
#pragma unroll
        for (int j = 0; j < 4; ++j)
          acc[i][j] = __builtin_amdgcn_mfma_f32_16x16x32_bf16(af[i], bfr[j], acc[i][j], 0, 0, 0);
    }
    __syncthreads();
  }

  const bool right = (n0 >= 256);
  unsigned short* Cb = right ? Cr : Cl;
  const int nc0 = n0 - (right ? 256 : 0);
#pragma unroll
  for (int i = 0; i < 4; ++i) {
    const int rbase = m0 + wm * 64 + i * 16 + quad * 4;
#pragma unroll
    for (int j = 0; j < 4; ++j) {
      const int col = nc0 + wn * 64 + j * 16 + lane16;
      const float bv = right ? b1[col] : 0.0f;
#pragma unroll
      for (int r = 0; r < 4; ++r)
        Cb[(size_t)(rbase + r) * HID_DIM + col] = f2bf(acc[i][j][r] + bv);
    }
  }
}

// GEMM2: BK=64 + swizzle; A k<256 from Am (mean2), k>=256 from Ah (h)
__global__ __launch_bounds__(256) void k_gemm2(const unsigned short* __restrict__ Am,
                                               const unsigned short* __restrict__ Ah,
                                               const unsigned short* __restrict__ B,
                                               float* __restrict__ out,
                                               const float* __restrict__ b2, int Mstore) {
  __shared__ unsigned short As[128 * 64];
  __shared__ unsigned short Bs[128 * 64];
  const int tid = threadIdx.x;
  const int w = tid >> 6, l = tid & 63;
  const int wm = w >> 1, wn = w & 1;
  const int quad = l >> 4, lane16 = l & 15;
  const int nwg = gridDim.x * gridDim.y;
  const int wg = xcd_swz(blockIdx.y * gridDim.x + blockIdx.x, nwg);
  const int m0 = (wg / gridDim.x) * 128;
  const int n0 = (wg % gridDim.x) * 128;

  int arow[4], acol[4];
  const unsigned short* bsrc[4];
#pragma unroll
  for (int it = 0; it < 4; ++it) {
    const int p_lin = (w * 4 + it) * 64 + l;
    const int row = p_lin >> 3;
    const int c = (p_lin & 7) ^ (row & 7);
    arow[it] = row; acol[it] = c * 8;
    bsrc[it] = B + (size_t)(n0 + row) * (2 * HID_DIM) + c * 8;
  }
  int arb[4], brb[4];
#pragma unroll
  for (int i = 0; i < 4; ++i) {
    arb[i] = wm * 64 + i * 16 + lane16;
    brb[i] = wn * 64 + i * 16 + lane16;
  }

  f32x4 acc[4][4] = {};
  for (int k0 = 0; k0 < 2 * HID_DIM; k0 += 64) {
    const unsigned short* Ab = (k0 < HID_DIM) ? Am + k0 : Ah + (k0 - HID_DIM);
#pragma unroll
    for (int it = 0; it < 4; ++it)
      load_lds16(Ab + (size_t)(m0 + arow[it]) * HID_DIM + acol[it],
                 (char*)As + ((w * 4 + it) << 10));
#pragma unroll
    for (int it = 0; it < 4; ++it)
      load_lds16(bsrc[it] + k0, (char*)Bs + ((w * 4 + it) << 10));
    __syncthreads();
#pragma unroll
    for (int kk = 0; kk < 2; ++kk) {
      bf16x8 af[4], bfr[4];
#pragma unroll
      for (int i = 0; i < 4; ++i) {
        const int r = arb[i];
        af[i] = *(const bf16x8*)((const char*)As + r * 128 +
                                 (((kk * 4 + quad) ^ (r & 7)) << 4));
      }
#pragma unroll
      for (int j = 0; j < 4; ++j) {
        const int r = brb[j];
        bfr[j] = *(const bf16x8*)((const char*)Bs + r * 128 +
                                  (((kk * 4 + quad) ^ (r & 7)) << 4));
      }
#pragma unroll
      for (int i = 0; i < 4; ++i)
#pragma unroll
        for (int j = 0; j < 4; ++j)
          acc[i][j] = __builtin_amdgcn_mfma_f32_16x16x32_bf16(af[i], bfr[j], acc[i][j], 0, 0, 0);
    }
    __syncthreads();
  }

#pragma unroll
  for (int i = 0; i < 4; ++i) {
    const int rbase = m0 + wm * 64 + i * 16 + quad * 4;
#pragma unroll
    for (int j = 0; j < 4; ++j) {
      const int col = n0 + wn * 64 + j * 16 + lane16;
      const float bv = b2[col];
#pragma unroll
      for (int r = 0; r < 4; ++r) {
        const int rowi = rbase + r;
        if (rowi < Mstore) out[(size_t)rowi * OUT_N + col] = acc[i][j][r] + bv;
      }
    }
  }
}

// ---------- aggregations: 1 wave/node, 16B/lane, 8/4/2/1-pair batch cascade ----------
template <int NB>
static __device__ __forceinline__ void gatherN(const unsigned short* __restrict__ src,
                                               const int* __restrict__ csr, int ib,
                                               size_t colb, float* a) {
  bf16x8 v[NB];
#pragma unroll
  for (int u = 0; u < NB; ++u) {
    int r = csr[ib + 2 * u];
    v[u] = *(const bf16x8*)&src[(size_t)r * HID_DIM + colb];
  }
#pragma unroll
  for (int u = 0; u < NB; ++u)
#pragma unroll
    for (int c = 0; c < 8; ++c) a[c] += bf2f((unsigned short)v[u][c]);
}

static __device__ __forceinline__ void agg_sum(const unsigned short* __restrict__ src,
                                               const int* __restrict__ csr,
                                               int s, int e, int half, size_t colb,
                                               float* a) {
  const int cnt = e - s;
  const int P = cnt >> 1;
  const int ib0 = s + half;
  int k = 0;
  for (; k + 8 <= P; k += 8) gatherN<8>(src, csr, ib0 + 2 * k, colb, a);
  if (k + 4 <= P) { gatherN<4>(src, csr, ib0 + 2 * k, colb, a); k += 4; }
  if (k + 2 <= P) { gatherN<2>(src, csr, ib0 + 2 * k, colb, a); k += 2; }
  if (k < P)      { gatherN<1>(src, csr, ib0 + 2 * k, colb, a); }
  if ((cnt & 1) && half == 0) {
    bf16x8 v = *(const bf16x8*)&src[(size_t)csr[e - 1] * HID_DIM + colb];
#pragma unroll
    for (int c = 0; c < 8; ++c) a[c] += bf2f((unsigned short)v[c]);
  }
#pragma unroll
  for (int c = 0; c < 8; ++c) a[c] += __shfl_xor(a[c], 32);
}

__global__ void k_agg1(const unsigned short* __restrict__ Cl,
                       const unsigned short* __restrict__ Cr,
                       const int* __restrict__ off, const int* __restrict__ csr,
                       unsigned short* __restrict__ h, int nNodes) {
  int node = blockIdx.x * 4 + (threadIdx.x >> 6);
  if (node >= nNodes) return;
  const int l = threadIdx.x & 63;
  const int half = l >> 5, li = l & 31;
  const size_t colb = (size_t)li * 8;
  int s = off[node], e = off[node + 1];
  float a[8] = {};
  agg_sum(Cl, csr, s, e, half, colb, a);
  if (half == 0) {
    float inv = 1.0f / fmaxf((float)(e - s), 1.0f);
    bf16x8 xr = *(const bf16x8*)&Cr[(size_t)node * HID_DIM + colb];   // includes b1
    bf16x8 o;
#pragma unroll
    for (int c = 0; c < 8; ++c)
      o[c] = (short)f2bf(fmaxf(a[c] * inv + bf2f((unsigned short)xr[c]), 0.0f));
    *(bf16x8*)&h[(size_t)node * HID_DIM + colb] = o;
  }
}

__global__ void k_agg2(const unsigned short* __restrict__ hsrc,
                       const int* __restrict__ off, const int* __restrict__ csr,
                       unsigned short* __restrict__ mean2, int nNodes) {
  int node = blockIdx.x * 4 + (threadIdx.x >> 6);
  if (node >= nNodes) return;
  const int l = threadIdx.x & 63;
  const int half = l >> 5, li = l & 31;
  const size_t colb = (size_t)li * 8;
  int s = off[node], e = off[node + 1];
  float a[8] = {};
  agg_sum(hsrc, csr, s, e, half, colb, a);
  if (half == 0) {
    float inv = 1.0f / fmaxf((float)(e - s), 1.0f);
    bf16x8 o;
#pragma unroll
    for (int c = 0; c < 8; ++c) o[c] = (short)f2bf(a[c] * inv);
    *(bf16x8*)&mean2[(size_t)node * HID_DIM + colb] = o;
  }
}

extern "C" void kernel_launch(void* const* d_in, const int* in_sizes, int n_in,
                              void* d_out, int out_size, void* d_ws, size_t ws_size,
                              hipStream_t stream) {
  const float* x   = (const float*)d_in[0];
  const void*  ei  = d_in[1];
  const float* w1l = (const float*)d_in[2];
  const float* w1r = (const float*)d_in[3];
  const float* b1  = (const float*)d_in[4];
  const float* w2l = (const float*)d_in[5];
  const float* w2r = (const float*)d_in[6];
  const float* b2  = (const float*)d_in[7];
  float* out = (float*)d_out;

  const int nN   = in_sizes[0] / IN_DIM;         // 50000
  const int nE   = in_sizes[1] / 2;              // 800000
  const int Mpad = (nN + 127) & ~127;            // 50048
  const int padN = (nN + 1023) & ~1023;          // 50176 (scan granularity)
  const int nb   = padN >> 10;                   // 49 scan blocks

  char* ws = (char*)d_ws;
  size_t o = 0;
  auto alloc = [&](size_t bytes) {
    char* p = ws + o;
    o += (bytes + 255) & ~(size_t)255;
    return p;
  };
  unsigned short* xbf   = (unsigned short*)alloc((size_t)Mpad * IN_DIM * 2);
  unsigned short* W1c   = (unsigned short*)alloc((size_t)2 * HID_DIM * IN_DIM * 2);
  unsigned short* W2c   = (unsigned short*)alloc((size_t)OUT_N * 2 * HID_DIM * 2);
  unsigned short* Cl    = (unsigned short*)alloc((size_t)Mpad * HID_DIM * 2);
  unsigned short* Cr    = (unsigned short*)alloc((size_t)Mpad * HID_DIM * 2);
  unsigned short* hbuf  = (unsigned short*)alloc((size_t)Mpad * HID_DIM * 2);
  unsigned short* mean2 = (unsigned short*)alloc((size_t)Mpad * HID_DIM * 2);
  int* deg    = (int*)alloc((size_t)padN * 4);         // zero-padded for int4 scan
  int* offs   = (int*)alloc((size_t)padN * 4);         // off[nN]=nE lands in pad region
  int* cursor = (int*)alloc((size_t)padN * 4);
  int* bsum   = (int*)alloc((size_t)1024 * 4);
  int* csr    = (int*)alloc((size_t)nE * 4);
  int* flag   = (int*)alloc(256);

  hipMemsetAsync(deg, 0, (size_t)padN * 4, stream);
  // pad rows of xbf / hbuf / mean2 stay 0xAA poison: decodes to ~1e-13 bf16,
  // flows only into pad rows of Cl/Cr/out-guarded stores -> never observed.

  const int n4  = nN * IN_DIM / 4;
  const int nxb = (n4 + 255) / 256;
  const int nEb = (nE + 255) / 256;
  const int ngemm = 4 * (Mpad / 128);            // 1564

  k_pre<<<769 + nxb + nEb, 256, 0, stream>>>((const unsigned int*)ei, ei, flag,
                                             w1l, w1r, W1c, w2l, w2r, W2c,
                                             x, xbf, n4, nxb, nE, deg);
  k_bsum<<<nb, 256, 0, stream>>>(deg, bsum);
  k_bscan<<<1, 1024, 0, stream>>>(bsum, nb);
  k_offsets<<<nb, 256, 0, stream>>>(deg, bsum, offs, cursor);
  k_g1f<<<ngemm + nEb, 256, 0, stream>>>(xbf, W1c, Cl, Cr, b1, ngemm,
                                         ei, nE, flag, cursor, csr);
  k_agg1<<<(nN + 3) / 4, 256, 0, stream>>>(Cl, Cr, offs, csr, hbuf, nN);
  k_agg2<<<(nN + 3) / 4, 256, 0, stream>>>(hbuf, offs, csr, mean2, nN);
  dim3 g2(512 / 128, Mpad / 128);
  k_gemm2<<<g2, 256, 0, stream>>>(mean2, hbuf, W2c, out, b2, nN);
}